// Round 4
// baseline (563.283 us; speedup 1.0000x reference)
//
#include <hip/hip_runtime.h>
#include <hip/hip_bf16.h>
#include <cstdint>
#include <cstddef>

#define B_ 4
#define T_ 2048
#define C_ 1024
#define H_ 16
#define D_ 64
#define M_ (B_*T_)   // 8192 rows

using bf16_t = __hip_bfloat16;
typedef __bf16 v8bf __attribute__((ext_vector_type(8)));
typedef float  v4f  __attribute__((ext_vector_type(4)));
typedef float  f32x16 __attribute__((ext_vector_type(16)));

// 1/sqrt(D) * log2(e): folded into Q at the QKV epilogue; softmax in exp2 domain.
#define QSCALE (0.125f * 1.44269504088896340736f)

static __device__ __forceinline__ bf16_t f2bf(float v){ return __float2bfloat16(v); }

// async global->LDS, 16B per lane. LDS dest is wave-uniform base + lane*16.
static __device__ __forceinline__ void glds16(const bf16_t* g, bf16_t* l){
  __builtin_amdgcn_global_load_lds((__attribute__((address_space(1))) void*)g,
                                   (__attribute__((address_space(3))) void*)l, 16, 0, 0);
}

static __device__ __forceinline__ uint32_t cvt_pk_bf16(float lo, float hi){
  uint32_t w;
  asm("v_cvt_pk_bf16_f32 %0, %1, %2" : "=v"(w) : "v"(lo), "v"(hi));
  return w;
}

// ---------------- transpose + cast fp32[K][N] -> bf16[N][K] ----------------
__global__ void k_transpose_cast(const float* __restrict__ in, bf16_t* __restrict__ out,
                                 int K, int N){
  __shared__ float tile[32][33];
  int k0 = blockIdx.y*32, n0 = blockIdx.x*32;
  int tx = threadIdx.x, ty = threadIdx.y; // 32 x 8
  #pragma unroll
  for(int j=0;j<32;j+=8) tile[ty+j][tx] = in[(size_t)(k0+ty+j)*N + n0+tx];
  __syncthreads();
  #pragma unroll
  for(int j=0;j<32;j+=8) out[(size_t)(n0+ty+j)*K + k0+tx] = f2bf(tile[tx][ty+j]);
}

// ---------------- LayerNorm fp32 row -> bf16 row ----------------
__global__ __launch_bounds__(256) void k_layernorm(const float* __restrict__ x,
                                                   const float* __restrict__ gamma,
                                                   const float* __restrict__ beta,
                                                   bf16_t* __restrict__ out){
  int row = blockIdx.x;
  int tid = threadIdx.x;
  const float4 v = reinterpret_cast<const float4*>(x + (size_t)row*C_)[tid];
  float s  = v.x+v.y+v.z+v.w;
  float ss = v.x*v.x+v.y*v.y+v.z*v.z+v.w*v.w;
  #pragma unroll
  for(int m=1;m<64;m<<=1){ s += __shfl_xor(s,m); ss += __shfl_xor(ss,m); }
  __shared__ float sbuf[4], ssbuf[4];
  int wid = tid>>6, lane = tid&63;
  if(lane==0){ sbuf[wid]=s; ssbuf[wid]=ss; }
  __syncthreads();
  s  = sbuf[0]+sbuf[1]+sbuf[2]+sbuf[3];
  ss = ssbuf[0]+ssbuf[1]+ssbuf[2]+ssbuf[3];
  float mean = s * (1.0f/C_);
  float var  = ss * (1.0f/C_) - mean*mean;
  float rstd = rsqrtf(var + 1e-3f);
  const float4 g = reinterpret_cast<const float4*>(gamma)[tid];
  const float4 b = reinterpret_cast<const float4*>(beta)[tid];
  union { ushort4 u; bf16_t h[4]; } pk;
  pk.h[0] = f2bf(g.x*(v.x-mean)*rstd + b.x);
  pk.h[1] = f2bf(g.y*(v.y-mean)*rstd + b.y);
  pk.h[2] = f2bf(g.z*(v.z-mean)*rstd + b.z);
  pk.h[3] = f2bf(g.w*(v.w-mean)*rstd + b.w);
  *reinterpret_cast<ushort4*>(out + (size_t)row*C_ + tid*4) = pk.u;
}

// ---------------- GEMM: 256x256 tile, BK=64, 8 waves, counted-vmcnt pipeline ----------------
// A[M][K]bf16 @ Bt[N][K]bf16.
// MODE 0: QKV split -> q*QSCALE[B,H,T,D], k[B,H,T,D], vt[B,H,D,T] (bf16)
// MODE 1: + bias + resid -> fp32 out
// MODE 2: + bias -> exact GELU -> bf16 out
// MODE 3: + bias + resid -> fp32 out (resid may alias out)
//
// LDS: As/Bs[2][256*64] (128 KiB total), double-buffered by K-tile parity.
// Buffer lifecycle (race-freedom): tile t lives in buf b=t&1. Iteration t:
//   (1) issue stage(t+1 -> b^1)   [b^1's last readers were iter t-1, before its
//                                  bottom barrier -> safe to overwrite]
//   (2) s_waitcnt vmcnt(8)        [waits tile t's 8 loads; t+1's 8 stay in flight]
//   (3) s_barrier                 [all waves confirmed their share of t landed]
//   (4) 4 MFMA quadrant-phases reading buf b (ds_reads drained into MFMAs)
//   (5) s_barrier                 [protects buf b: iter t+1 stages t+2 into b]
// LDS XOR swizzle (T2): logical (row, 16B-slot sl) stored at phys slot sl^(row&7);
// global_load_lds dest stays linear, the SOURCE address is inverse-swizzled, and
// reads apply the same XOR (rule #21 both-sides).
template<int MODE>
__global__ __launch_bounds__(512)
void k_gemm(const bf16_t* __restrict__ A, const bf16_t* __restrict__ Bt,
            const float* __restrict__ bias, const float* resid,
            void* out0, void* out1, void* out2,
            int N, int K, int gx)
{
  __shared__ __align__(16) bf16_t As[2][256*64];
  __shared__ __align__(16) bf16_t Bs[2][256*64];
  const int tid = threadIdx.x, lane = tid & 63, w = tid >> 6;   // 8 waves
  const int wm = w >> 2, wn = w & 3;                            // 2M x 4N

  // XCD-aware bijective swizzle (nwg % 8 == 0 for all our shapes), row-tile chunks per XCD
  const int nwg = gx * 32;
  const int orig = blockIdx.y * gx + blockIdx.x;
  const int swz = (orig & 7) * (nwg >> 3) + (orig >> 3);
  const int ct = swz % gx, rt = swz / gx;
  const int row0 = rt * 256, col0 = ct * 256;

  // staging: wave w, instr i covers phys bytes [w*1024 + i*8192, +1024)
  const int sswz = (lane & 7) ^ (lane >> 3);   // inverse-swizzled source slot
  const int srow = w * 8 + (lane >> 3);        // + i*64
  const bf16_t* Ag = A  + (size_t)(row0 + srow) * K + sswz * 8;
  const bf16_t* Bg = Bt + (size_t)(col0 + srow) * K + sswz * 8;
  const int lbase = w * 512;                   // elements; + i*4096

  v4f acc[8][4] = {};
  const int NT = K >> 6;

  auto stage = [&](int tt, int bb){
    const size_t ko = (size_t)tt * 64;
    #pragma unroll
    for (int i = 0; i < 4; ++i) {
      glds16(Ag + (size_t)(i*64) * K + ko, &As[bb][lbase + i*4096]);
      glds16(Bg + (size_t)(i*64) * K + ko, &Bs[bb][lbase + i*4096]);
    }
  };

  stage(0, 0);
  for (int t = 0; t < NT; ++t) {
    const int b = t & 1;
    if (t + 1 < NT) {
      stage(t + 1, b ^ 1);
      asm volatile("s_waitcnt vmcnt(8)" ::: "memory");
    } else {
      asm volatile("s_waitcnt vmcnt(0)" ::: "memory");
    }
    __builtin_amdgcn_s_barrier();
    __builtin_amdgcn_sched_barrier(0);
    const bf16_t* Ab = &As[b][0];
    const bf16_t* Bb = &Bs[b][0];
    #pragma unroll
    for (int mq = 0; mq < 2; ++mq) {
      v8bf af[4][2];
      #pragma unroll
      for (int m = 0; m < 4; ++m)
        #pragma unroll
        for (int kk = 0; kk < 2; ++kk) {
          const int r  = wm*128 + mq*64 + m*16 + (lane & 15);
          const int sl = kk*4 + (lane >> 4);
          af[m][kk] = *reinterpret_cast<const v8bf*>(Ab + r*64 + ((sl ^ (lane & 7)) * 8));
        }
      #pragma unroll
      for (int nq = 0; nq < 2; ++nq) {
        v8bf bfv[2][2];
        #pragma unroll
        for (int n = 0; n < 2; ++n)
          #pragma unroll
          for (int kk = 0; kk < 2; ++kk) {
            const int r  = wn*64 + (nq*2+n)*16 + (lane & 15);
            const int sl = kk*4 + (lane >> 4);
            bfv[n][kk] = *reinterpret_cast<const v8bf*>(Bb + r*64 + ((sl ^ (lane & 7)) * 8));
          }
        __builtin_amdgcn_s_setprio(1);
        #pragma unroll
        for (int kk = 0; kk < 2; ++kk)
          #pragma unroll
          for (int m = 0; m < 4; ++m)
            #pragma unroll
            for (int n = 0; n < 2; ++n)
              acc[mq*4+m][nq*2+n] = __builtin_amdgcn_mfma_f32_16x16x32_bf16(
                  af[m][kk], bfv[n][kk], acc[mq*4+m][nq*2+n], 0,0,0);
        __builtin_amdgcn_s_setprio(0);
      }
    }
    __builtin_amdgcn_sched_barrier(0);
    __builtin_amdgcn_s_barrier();
  }

  // epilogue: D[row=(lane>>4)*4+i][col=lane&15] per 16x16 frag
  #pragma unroll
  for (int mf = 0; mf < 8; ++mf) {
    const int rbase = row0 + wm*128 + mf*16 + (lane>>4)*4;
    #pragma unroll
    for (int nf = 0; nf < 4; ++nf) {
      const int c = col0 + wn*64 + nf*16 + (lane&15);
      #pragma unroll
      for (int i = 0; i < 4; ++i) {
        const int rr = rbase + i;
        float v = acc[mf][nf][i];
        if constexpr(MODE==0){
          const int sec = c >> 10, cc = c & 1023;
          const int h = cc >> 6, d = cc & 63;
          const int b = rr >> 11, t = rr & 2047;
          if(sec==0)      ((bf16_t*)out0)[((size_t)(b*H_ + h)*T_ + t)*D_ + d] = f2bf(v * QSCALE);
          else if(sec==1) ((bf16_t*)out1)[((size_t)(b*H_ + h)*T_ + t)*D_ + d] = f2bf(v);
          else            ((bf16_t*)out2)[((size_t)(b*H_ + h)*D_ + d)*T_ + t] = f2bf(v);
        } else if constexpr(MODE==1){
          ((float*)out0)[(size_t)rr*N + c] = v + bias[c] + resid[(size_t)rr*N + c];
        } else if constexpr(MODE==2){
          float o = v + bias[c];
          o = 0.5f*o*(1.0f + erff(o*0.70710678118f));
          ((bf16_t*)out0)[(size_t)rr*N + c] = f2bf(o);
        } else {
          ((float*)out0)[(size_t)rr*N + c] = v + bias[c] + resid[(size_t)rr*N + c];
        }
      }
    }
  }
}

// ---------------- causal flash attention, swapped-operand 32x32 ----------------
// Q(pre-scaled): [B,H,T,D] bf16 ; K: [B,H,T,D] bf16 ; Vt: [B,H,D,T] bf16 ; O: [B,T,C] bf16
__global__ __launch_bounds__(256)
void k_attn(const bf16_t* __restrict__ Q, const bf16_t* __restrict__ Kg,
            const bf16_t* __restrict__ Vt, bf16_t* __restrict__ O)
{
  __shared__ __align__(16) bf16_t Ks [64][72];   // [kv][d]
  __shared__ __align__(16) bf16_t Vts[64][72];   // [d][kv]
  __shared__ __align__(16) bf16_t Os [128][72];  // [q][d] transpose buffer
  const int bh = blockIdx.y;
  const int qt = blockIdx.x;
  const int tid = threadIdx.x, lane = tid & 63, w = tid >> 6;
  const int ql = lane & 31, hi = lane >> 5;
  const int qbase = qt*128 + w*32;
  const int q = qbase + ql;

  v8bf qf[4];
  {
    const bf16_t* Qb = Q + ((size_t)bh*T_ + q)*D_ + hi*8;
    #pragma unroll
    for(int ds=0; ds<4; ds++)
      qf[ds] = *reinterpret_cast<const v8bf*>(Qb + ds*16);
  }

  f32x16 accO[2] = {};          // O^T: col=q (lane-local), row d = dh*32 + (r&3)+8*(r>>2)+4*hi
  float mrun = -1e30f, lrun = 0.0f;

  const int NT = (qt + 1) * 2;  // 64-wide kv tiles
  const int srow = tid >> 2;
  const int scol = (tid & 3) * 16;
  const bf16_t* Kgp = Kg + ((size_t)bh*T_ + srow)*D_ + scol;
  const bf16_t* Vtp = Vt + ((size_t)bh*D_ + srow)*T_ + scol;

  for(int t=0; t<NT; t++){
    const int kv0 = t*64;
    *reinterpret_cast<v8bf*>(&Ks [srow][scol  ]) = *reinterpret_cast<const v8bf*>(Kgp + (size_t)kv0*D_);
    *reinterpret_cast<v8bf*>(&Ks [srow][scol+8]) = *reinterpret_cast<const v8bf*>(Kgp + (size_t)kv0*D_ + 8);
    *reinterpret_cast<v8bf*>(&Vts[srow][scol  ]) = *reinterpret_cast<const v8bf*>(Vtp + kv0);
    *reinterpret_cast<v8bf*>(&Vts[srow][scol+8]) = *reinterpret_cast<const v8bf*>(Vtp + kv0 + 8);
    __syncthreads();

    if(kv0 <= qbase + 31){
      f32x16 sT[2] = {};
      #pragma unroll
      for(int kvh=0; kvh<2; kvh++)
        #pragma unroll
        for(int ds=0; ds<4; ds++){
          v8bf kf = *reinterpret_cast<const v8bf*>(&Ks[kvh*32 + ql][ds*16 + hi*8]);
          sT[kvh] = __builtin_amdgcn_mfma_f32_32x32x16_bf16(kf, qf[ds], sT[kvh], 0,0,0);
        }

      if(kv0 + 63 > qbase){
        const int qrel = q - kv0 - hi*4;
        #pragma unroll
        for(int kvh=0; kvh<2; kvh++)
          #pragma unroll
          for(int r=0; r<16; r++){
            const int c = kvh*32 + (r&3) + 8*(r>>2);
            if(c > qrel) sT[kvh][r] = -1e30f;
          }
      }

      float pm = sT[0][0];
      #pragma unroll
      for(int r=1; r<16; r++) pm = fmaxf(pm, sT[0][r]);
      #pragma unroll
      for(int r=0; r<16; r++) pm = fmaxf(pm, sT[1][r]);
      pm = fmaxf(pm, __shfl_xor(pm, 32));
      const float mnew = fmaxf(mrun, pm);
      const float corr = __builtin_amdgcn_exp2f(mrun - mnew);
      mrun = mnew;
      float rs = 0.0f;
      #pragma unroll
      for(int kvh=0; kvh<2; kvh++)
        #pragma unroll
        for(int r=0; r<16; r++){
          float p = __builtin_amdgcn_exp2f(sT[kvh][r] - mnew);
          sT[kvh][r] = p;
          rs += p;
        }
      rs += __shfl_xor(rs, 32);
      lrun = lrun*corr + rs;
      #pragma unroll
      for(int dh=0; dh<2; dh++)
        #pragma unroll
        for(int r=0; r<16; r++) accO[dh][r] *= corr;

      v8bf pfrag[4];
      #pragma unroll
      for(int s4=0; s4<4; s4++){
        const int kvh = s4>>1, bb = (s4&1)*8;
        uint32_t wa = cvt_pk_bf16(sT[kvh][bb+0], sT[kvh][bb+1]);
        uint32_t wb = cvt_pk_bf16(sT[kvh][bb+2], sT[kvh][bb+3]);
        uint32_t wc = cvt_pk_bf16(sT[kvh][bb+4], sT[kvh][bb+5]);
        uint32_t wd = cvt_pk_bf16(sT[kvh][bb+6], sT[kvh][bb+7]);
        uint32_t xwa = (uint32_t)__shfl_xor((int)wa, 32);
        uint32_t xwb = (uint32_t)__shfl_xor((int)wb, 32);
        uint32_t xwc = (uint32_t)__shfl_xor((int)wc, 32);
        uint32_t xwd = (uint32_t)__shfl_xor((int)wd, 32);
        union { uint32_t u[4]; v8bf v; } pk;
        pk.u[0] = hi ? xwc : wa;
        pk.u[1] = hi ? xwd : wb;
        pk.u[2] = hi ? wc  : xwa;
        pk.u[3] = hi ? wd  : xwb;
        pfrag[s4] = pk.v;
      }

      #pragma unroll
      for(int dh=0; dh<2; dh++)
        #pragma unroll
        for(int s4=0; s4<4; s4++){
          v8bf vf = *reinterpret_cast<const v8bf*>(&Vts[dh*32 + ql][s4*16 + hi*8]);
          accO[dh] = __builtin_amdgcn_mfma_f32_32x32x16_bf16(vf, pfrag[s4], accO[dh], 0,0,0);
        }
    }
    __syncthreads();
  }

  const float inv = 1.0f / lrun;
  #pragma unroll
  for(int dh=0; dh<2; dh++)
    #pragma unroll
    for(int rg=0; rg<4; rg++){
      uint32_t lo_ = cvt_pk_bf16(accO[dh][rg*4+0]*inv, accO[dh][rg*4+1]*inv);
      uint32_t hi_ = cvt_pk_bf16(accO[dh][rg*4+2]*inv, accO[dh][rg*4+3]*inv);
      uint2 w2; w2.x = lo_; w2.y = hi_;
      *reinterpret_cast<uint2*>(&Os[w*32 + ql][dh*32 + rg*8 + hi*4]) = w2;
    }
  __syncthreads();
  const int b = bh >> 4, h = bh & 15;
  const int orow = tid >> 1, ocol = (tid & 1) * 32;
  bf16_t* Og = O + ((size_t)(b*T_ + qt*128 + orow))*C_ + h*64 + ocol;
  #pragma unroll
  for(int j=0;j<4;j++)
    *reinterpret_cast<v8bf*>(Og + j*8) = *reinterpret_cast<const v8bf*>(&Os[orow][ocol + j*8]);
}

// ---------------- launch ----------------
extern "C" void kernel_launch(void* const* d_in, const int* in_sizes, int n_in,
                              void* d_out, int out_size, void* d_ws, size_t ws_size,
                              hipStream_t stream) {
  const float* x      = (const float*)d_in[0];
  const float* w_qkv  = (const float*)d_in[1];
  const float* w_proj = (const float*)d_in[2];
  const float* b_proj = (const float*)d_in[3];
  const float* w1     = (const float*)d_in[4];
  const float* b1     = (const float*)d_in[5];
  const float* w2     = (const float*)d_in[6];
  const float* b2     = (const float*)d_in[7];
  const float* gamma1 = (const float*)d_in[8];
  const float* beta1  = (const float*)d_in[9];
  const float* gamma2 = (const float*)d_in[10];
  const float* beta2  = (const float*)d_in[11];

  char* ws = (char*)d_ws;
  bf16_t* wqkv_t  = (bf16_t*)(ws + 0);           // 3072x1024
  bf16_t* wproj_t = (bf16_t*)(ws + 6291456);     // 1024x1024
  bf16_t* w1_t    = (bf16_t*)(ws + 8388608);     // 4096x1024
  bf16_t* w2_t    = (bf16_t*)(ws + 16777216);    // 1024x4096
  bf16_t* qb      = (bf16_t*)(ws + 25165824);    // [B,H,T,D]
  bf16_t* kb      = (bf16_t*)(ws + 41943040);    // [B,H,T,D]
  bf16_t* vtb     = (bf16_t*)(ws + 58720256);    // [B,H,D,T]
  bf16_t* obuf    = (bf16_t*)(ws + 75497472);    // [B,T,C]
  bf16_t* hb      = (bf16_t*)(ws + 92274688);    // [M,C] bf16
  bf16_t* gb      = (bf16_t*)(ws + 25165824);    // [M,4C] bf16 (reuses q..o)
  float*  x2      = (float*)d_out;               // x after attn residual (aliases out)

  dim3 tb(32,8);
  k_transpose_cast<<<dim3(3072/32, 1024/32), tb, 0, stream>>>(w_qkv,  wqkv_t, 1024, 3072);
  k_transpose_cast<<<dim3(1024/32, 1024/32), tb, 0, stream>>>(w_proj, wproj_t,1024, 1024);
  k_transpose_cast<<<dim3(4096/32, 1024/32), tb, 0, stream>>>(w1,     w1_t,   1024, 4096);
  k_transpose_cast<<<dim3(1024/32, 4096/32), tb, 0, stream>>>(w2,     w2_t,   4096, 1024);

  k_layernorm<<<M_, 256, 0, stream>>>(x, gamma1, beta1, hb);

  k_gemm<0><<<dim3(12, 32), 512, 0, stream>>>(hb, wqkv_t, nullptr, nullptr,
                                              qb, kb, vtb, 3072, 1024, 12);
  k_attn<<<dim3(T_/128, B_*H_), 256, 0, stream>>>(qb, kb, vtb, obuf);

  k_gemm<1><<<dim3(4, 32), 512, 0, stream>>>(obuf, wproj_t, b_proj, x,
                                             x2, nullptr, nullptr, 1024, 1024, 4);
  k_layernorm<<<M_, 256, 0, stream>>>(x2, gamma2, beta2, hb);

  k_gemm<2><<<dim3(16, 32), 512, 0, stream>>>(hb, w1_t, b1, nullptr,
                                              gb, nullptr, nullptr, 4096, 1024, 16);
  k_gemm<3><<<dim3(4, 32), 512, 0, stream>>>(gb, w2_t, b2, x2,
                                             d_out, nullptr, nullptr, 1024, 4096, 4);
}

// Round 5
// 487.455 us; speedup vs baseline: 1.1556x; 1.1556x over previous
//
#include <hip/hip_runtime.h>
#include <hip/hip_bf16.h>
#include <cstdint>
#include <cstddef>

#define B_ 4
#define T_ 2048
#define C_ 1024
#define H_ 16
#define D_ 64
#define M_ (B_*T_)   // 8192 rows

using bf16_t = __hip_bfloat16;
typedef __bf16 v8bf __attribute__((ext_vector_type(8)));
typedef float  v4f  __attribute__((ext_vector_type(4)));
typedef float  f32x16 __attribute__((ext_vector_type(16)));

// 1/sqrt(D) * log2(e): folded into Q at the QKV epilogue; softmax in exp2 domain.
#define QSCALE (0.125f * 1.44269504088896340736f)

static __device__ __forceinline__ bf16_t f2bf(float v){ return __float2bfloat16(v); }

// async global->LDS, 16B per lane. LDS dest is wave-uniform base + lane*16.
static __device__ __forceinline__ void glds16(const bf16_t* g, bf16_t* l){
  __builtin_amdgcn_global_load_lds((__attribute__((address_space(1))) void*)g,
                                   (__attribute__((address_space(3))) void*)l, 16, 0, 0);
}

static __device__ __forceinline__ uint32_t cvt_pk_bf16(float lo, float hi){
  uint32_t w;
  asm("v_cvt_pk_bf16_f32 %0, %1, %2" : "=v"(w) : "v"(lo), "v"(hi));
  return w;
}

// ---------------- transpose + cast fp32[K][N] -> bf16[N][K] ----------------
__global__ void k_transpose_cast(const float* __restrict__ in, bf16_t* __restrict__ out,
                                 int K, int N){
  __shared__ float tile[32][33];
  int k0 = blockIdx.y*32, n0 = blockIdx.x*32;
  int tx = threadIdx.x, ty = threadIdx.y; // 32 x 8
  #pragma unroll
  for(int j=0;j<32;j+=8) tile[ty+j][tx] = in[(size_t)(k0+ty+j)*N + n0+tx];
  __syncthreads();
  #pragma unroll
  for(int j=0;j<32;j+=8) out[(size_t)(n0+ty+j)*K + k0+tx] = f2bf(tile[tx][ty+j]);
}

// ---------------- LayerNorm fp32 row -> bf16 row ----------------
__global__ __launch_bounds__(256) void k_layernorm(const float* __restrict__ x,
                                                   const float* __restrict__ gamma,
                                                   const float* __restrict__ beta,
                                                   bf16_t* __restrict__ out){
  int row = blockIdx.x;
  int tid = threadIdx.x;
  const float4 v = reinterpret_cast<const float4*>(x + (size_t)row*C_)[tid];
  float s  = v.x+v.y+v.z+v.w;
  float ss = v.x*v.x+v.y*v.y+v.z*v.z+v.w*v.w;
  #pragma unroll
  for(int m=1;m<64;m<<=1){ s += __shfl_xor(s,m); ss += __shfl_xor(ss,m); }
  __shared__ float sbuf[4], ssbuf[4];
  int wid = tid>>6, lane = tid&63;
  if(lane==0){ sbuf[wid]=s; ssbuf[wid]=ss; }
  __syncthreads();
  s  = sbuf[0]+sbuf[1]+sbuf[2]+sbuf[3];
  ss = ssbuf[0]+ssbuf[1]+ssbuf[2]+ssbuf[3];
  float mean = s * (1.0f/C_);
  float var  = ss * (1.0f/C_) - mean*mean;
  float rstd = rsqrtf(var + 1e-3f);
  const float4 g = reinterpret_cast<const float4*>(gamma)[tid];
  const float4 b = reinterpret_cast<const float4*>(beta)[tid];
  union { ushort4 u; bf16_t h[4]; } pk;
  pk.h[0] = f2bf(g.x*(v.x-mean)*rstd + b.x);
  pk.h[1] = f2bf(g.y*(v.y-mean)*rstd + b.y);
  pk.h[2] = f2bf(g.z*(v.z-mean)*rstd + b.z);
  pk.h[3] = f2bf(g.w*(v.w-mean)*rstd + b.w);
  *reinterpret_cast<ushort4*>(out + (size_t)row*C_ + tid*4) = pk.u;
}

// ---------------- GEMM: 256x128 tile, BK=32, 8 waves, counted-vmcnt double-buffer ----------------
// A[M][K]bf16 @ Bt[N][K]bf16.
// MODE 0: QKV split -> q*QSCALE[B,H,T,D], k[B,H,T,D], vt[B,H,D,T] (bf16)
// MODE 1: + bias + resid -> fp32 out
// MODE 2: + bias -> exact GELU -> bf16 out
// MODE 3: + bias + resid -> fp32 out (resid may alias out)
//
// Geometry: every GEMM shape here gives >=256 workgroups (full machine), and
// LDS = 2*(16+8) KiB = 48 KiB -> 2 blocks/CU (16 waves/CU) for latency hiding.
// Buffer lifecycle (race-freedom), tile t in buf b=t&1:
//   (1) stage(t+1 -> b^1)   [b^1 last read in iter t-1, before its bottom barrier]
//   (2) s_waitcnt vmcnt(3)  [waits own tile-t loads; t+1's 3 stay in flight]
//   (3) s_barrier           [all waves' tile-t data landed]
//   (4) MFMA phase reads buf b (ds_reads consumed by MFMAs before (5))
//   (5) s_barrier           [protects buf b before iter t+1 stages t+2 into it]
// LDS XOR swizzle (both-sides, rule #21): logical (row, 16B-slot sl) stored at
// phys slot sl^((row>>1)&3). glds16 dest stays linear; SOURCE address is
// inverse-swizzled; reads apply the same XOR. Worst-case 2-way aliasing (free).
template<int MODE>
__global__ __launch_bounds__(512, 4)
void k_gemm(const bf16_t* __restrict__ A, const bf16_t* __restrict__ Bt,
            const float* __restrict__ bias, const float* resid,
            void* out0, void* out1, void* out2,
            int N, int K, int gx)
{
  __shared__ __align__(16) bf16_t As[2][256*32];
  __shared__ __align__(16) bf16_t Bs[2][128*32];
  const int tid = threadIdx.x, lane = tid & 63, w = tid >> 6;   // 8 waves
  const int wm = w >> 1, wn = w & 1;                            // 4M x 2N, 64x64 each

  // XCD-aware bijective swizzle (nwg % 8 == 0 for all shapes), chunked
  const int nwg = gx * 32;
  const int orig = blockIdx.y * gx + blockIdx.x;
  const int swz = (orig & 7) * (nwg >> 3) + (orig >> 3);
  const int ct = swz % gx, rt = swz / gx;
  const int row0 = rt * 256, col0 = ct * 128;

  // staging addresses: lane covers phys (row = base + l>>2, slot = l&3);
  // inverse-swizzled global source slot = (l&3) ^ ((l>>3)&3)
  const int sswz  = ((lane & 3) ^ ((lane >> 3) & 3)) * 8;
  const int srowA = w * 32 + (lane >> 2);
  const int srowB = w * 16 + (lane >> 2);
  const bf16_t* Ag = A  + (size_t)(row0 + srowA) * K + sswz;
  const bf16_t* Bg = Bt + (size_t)(col0 + srowB) * K + sswz;

  // read-side swizzled 16B slot offset (elements), lane-only (row base bits vanish)
  const int rdswz = (((lane >> 4) ^ (((lane & 15) >> 1) & 3))) * 8;

  v4f acc[4][4] = {};
  const int NT = K >> 5;

  auto stage = [&](int tt, int bb){
    const size_t ko = (size_t)tt * 32;
    glds16(Ag + ko,                 &As[bb][(w*32     )*32]);
    glds16(Ag + (size_t)16*K + ko,  &As[bb][(w*32 + 16)*32]);
    glds16(Bg + ko,                 &Bs[bb][(w*16     )*32]);
  };

  stage(0, 0);
  for (int t = 0; t < NT; ++t) {
    const int b = t & 1;
    if (t + 1 < NT) {
      stage(t + 1, b ^ 1);
      asm volatile("s_waitcnt vmcnt(3)" ::: "memory");
    } else {
      asm volatile("s_waitcnt vmcnt(0)" ::: "memory");
    }
    __builtin_amdgcn_s_barrier();
    __builtin_amdgcn_sched_barrier(0);
    const bf16_t* Ab = &As[b][0];
    const bf16_t* Bb = &Bs[b][0];
    v8bf af[4], bfv[4];
    #pragma unroll
    for (int m = 0; m < 4; ++m) {
      const int r = wm*64 + m*16 + (lane & 15);
      af[m] = *reinterpret_cast<const v8bf*>(Ab + r*32 + rdswz);
    }
    #pragma unroll
    for (int n = 0; n < 4; ++n) {
      const int r = wn*64 + n*16 + (lane & 15);
      bfv[n] = *reinterpret_cast<const v8bf*>(Bb + r*32 + rdswz);
    }
    __builtin_amdgcn_s_setprio(1);
    #pragma unroll
    for (int m = 0; m < 4; ++m)
      #pragma unroll
      for (int n = 0; n < 4; ++n)
        acc[m][n] = __builtin_amdgcn_mfma_f32_16x16x32_bf16(af[m], bfv[n], acc[m][n], 0,0,0);
    __builtin_amdgcn_s_setprio(0);
    __builtin_amdgcn_sched_barrier(0);
    __builtin_amdgcn_s_barrier();
  }

  // epilogue: D[row=(lane>>4)*4+i][col=lane&15] per 16x16 frag
  #pragma unroll
  for (int mf = 0; mf < 4; ++mf) {
    const int rbase = row0 + wm*64 + mf*16 + (lane>>4)*4;
    #pragma unroll
    for (int nf = 0; nf < 4; ++nf) {
      const int c = col0 + wn*64 + nf*16 + (lane&15);
      #pragma unroll
      for (int i = 0; i < 4; ++i) {
        const int rr = rbase + i;
        float v = acc[mf][nf][i];
        if constexpr(MODE==0){
          const int sec = c >> 10, cc = c & 1023;
          const int h = cc >> 6, d = cc & 63;
          const int b = rr >> 11, t = rr & 2047;
          if(sec==0)      ((bf16_t*)out0)[((size_t)(b*H_ + h)*T_ + t)*D_ + d] = f2bf(v * QSCALE);
          else if(sec==1) ((bf16_t*)out1)[((size_t)(b*H_ + h)*T_ + t)*D_ + d] = f2bf(v);
          else            ((bf16_t*)out2)[((size_t)(b*H_ + h)*D_ + d)*T_ + t] = f2bf(v);
        } else if constexpr(MODE==1){
          ((float*)out0)[(size_t)rr*N + c] = v + bias[c] + resid[(size_t)rr*N + c];
        } else if constexpr(MODE==2){
          float o = v + bias[c];
          o = 0.5f*o*(1.0f + erff(o*0.70710678118f));
          ((bf16_t*)out0)[(size_t)rr*N + c] = f2bf(o);
        } else {
          ((float*)out0)[(size_t)rr*N + c] = v + bias[c] + resid[(size_t)rr*N + c];
        }
      }
    }
  }
}

// ---------------- causal flash attention, swapped-operand 32x32 ----------------
// Q(pre-scaled): [B,H,T,D] bf16 ; K: [B,H,T,D] bf16 ; Vt: [B,H,D,T] bf16 ; O: [B,T,C] bf16
__global__ __launch_bounds__(256)
void k_attn(const bf16_t* __restrict__ Q, const bf16_t* __restrict__ Kg,
            const bf16_t* __restrict__ Vt, bf16_t* __restrict__ O)
{
  __shared__ __align__(16) bf16_t Ks [64][72];   // [kv][d]
  __shared__ __align__(16) bf16_t Vts[64][72];   // [d][kv]
  __shared__ __align__(16) bf16_t Os [128][72];  // [q][d] transpose buffer
  const int bh = blockIdx.y;
  const int qt = blockIdx.x;
  const int tid = threadIdx.x, lane = tid & 63, w = tid >> 6;
  const int ql = lane & 31, hi = lane >> 5;
  const int qbase = qt*128 + w*32;
  const int q = qbase + ql;

  v8bf qf[4];
  {
    const bf16_t* Qb = Q + ((size_t)bh*T_ + q)*D_ + hi*8;
    #pragma unroll
    for(int ds=0; ds<4; ds++)
      qf[ds] = *reinterpret_cast<const v8bf*>(Qb + ds*16);
  }

  f32x16 accO[2] = {};          // O^T: col=q (lane-local), row d = dh*32 + (r&3)+8*(r>>2)+4*hi
  float mrun = -1e30f, lrun = 0.0f;

  const int NT = (qt + 1) * 2;  // 64-wide kv tiles
  const int srow = tid >> 2;
  const int scol = (tid & 3) * 16;
  const bf16_t* Kgp = Kg + ((size_t)bh*T_ + srow)*D_ + scol;
  const bf16_t* Vtp = Vt + ((size_t)bh*D_ + srow)*T_ + scol;

  for(int t=0; t<NT; t++){
    const int kv0 = t*64;
    *reinterpret_cast<v8bf*>(&Ks [srow][scol  ]) = *reinterpret_cast<const v8bf*>(Kgp + (size_t)kv0*D_);
    *reinterpret_cast<v8bf*>(&Ks [srow][scol+8]) = *reinterpret_cast<const v8bf*>(Kgp + (size_t)kv0*D_ + 8);
    *reinterpret_cast<v8bf*>(&Vts[srow][scol  ]) = *reinterpret_cast<const v8bf*>(Vtp + kv0);
    *reinterpret_cast<v8bf*>(&Vts[srow][scol+8]) = *reinterpret_cast<const v8bf*>(Vtp + kv0 + 8);
    __syncthreads();

    if(kv0 <= qbase + 31){
      f32x16 sT[2] = {};
      #pragma unroll
      for(int kvh=0; kvh<2; kvh++)
        #pragma unroll
        for(int ds=0; ds<4; ds++){
          v8bf kf = *reinterpret_cast<const v8bf*>(&Ks[kvh*32 + ql][ds*16 + hi*8]);
          sT[kvh] = __builtin_amdgcn_mfma_f32_32x32x16_bf16(kf, qf[ds], sT[kvh], 0,0,0);
        }

      if(kv0 + 63 > qbase){
        const int qrel = q - kv0 - hi*4;
        #pragma unroll
        for(int kvh=0; kvh<2; kvh++)
          #pragma unroll
          for(int r=0; r<16; r++){
            const int c = kvh*32 + (r&3) + 8*(r>>2);
            if(c > qrel) sT[kvh][r] = -1e30f;
          }
      }

      float pm = sT[0][0];
      #pragma unroll
      for(int r=1; r<16; r++) pm = fmaxf(pm, sT[0][r]);
      #pragma unroll
      for(int r=0; r<16; r++) pm = fmaxf(pm, sT[1][r]);
      pm = fmaxf(pm, __shfl_xor(pm, 32));
      const float mnew = fmaxf(mrun, pm);
      const float corr = __builtin_amdgcn_exp2f(mrun - mnew);
      mrun = mnew;
      float rs = 0.0f;
      #pragma unroll
      for(int kvh=0; kvh<2; kvh++)
        #pragma unroll
        for(int r=0; r<16; r++){
          float p = __builtin_amdgcn_exp2f(sT[kvh][r] - mnew);
          sT[kvh][r] = p;
          rs += p;
        }
      rs += __shfl_xor(rs, 32);
      lrun = lrun*corr + rs;
      #pragma unroll
      for(int dh=0; dh<2; dh++)
        #pragma unroll
        for(int r=0; r<16; r++) accO[dh][r] *= corr;

      v8bf pfrag[4];
      #pragma unroll
      for(int s4=0; s4<4; s4++){
        const int kvh = s4>>1, bb = (s4&1)*8;
        uint32_t wa = cvt_pk_bf16(sT[kvh][bb+0], sT[kvh][bb+1]);
        uint32_t wb = cvt_pk_bf16(sT[kvh][bb+2], sT[kvh][bb+3]);
        uint32_t wc = cvt_pk_bf16(sT[kvh][bb+4], sT[kvh][bb+5]);
        uint32_t wd = cvt_pk_bf16(sT[kvh][bb+6], sT[kvh][bb+7]);
        uint32_t xwa = (uint32_t)__shfl_xor((int)wa, 32);
        uint32_t xwb = (uint32_t)__shfl_xor((int)wb, 32);
        uint32_t xwc = (uint32_t)__shfl_xor((int)wc, 32);
        uint32_t xwd = (uint32_t)__shfl_xor((int)wd, 32);
        union { uint32_t u[4]; v8bf v; } pk;
        pk.u[0] = hi ? xwc : wa;
        pk.u[1] = hi ? xwd : wb;
        pk.u[2] = hi ? wc  : xwa;
        pk.u[3] = hi ? wd  : xwb;
        pfrag[s4] = pk.v;
      }

      #pragma unroll
      for(int dh=0; dh<2; dh++)
        #pragma unroll
        for(int s4=0; s4<4; s4++){
          v8bf vf = *reinterpret_cast<const v8bf*>(&Vts[dh*32 + ql][s4*16 + hi*8]);
          accO[dh] = __builtin_amdgcn_mfma_f32_32x32x16_bf16(vf, pfrag[s4], accO[dh], 0,0,0);
        }
    }
    __syncthreads();
  }

  const float inv = 1.0f / lrun;
  #pragma unroll
  for(int dh=0; dh<2; dh++)
    #pragma unroll
    for(int rg=0; rg<4; rg++){
      uint32_t lo_ = cvt_pk_bf16(accO[dh][rg*4+0]*inv, accO[dh][rg*4+1]*inv);
      uint32_t hi_ = cvt_pk_bf16(accO[dh][rg*4+2]*inv, accO[dh][rg*4+3]*inv);
      uint2 w2; w2.x = lo_; w2.y = hi_;
      *reinterpret_cast<uint2*>(&Os[w*32 + ql][dh*32 + rg*8 + hi*4]) = w2;
    }
  __syncthreads();
  const int b = bh >> 4, h = bh & 15;
  const int orow = tid >> 1, ocol = (tid & 1) * 32;
  bf16_t* Og = O + ((size_t)(b*T_ + qt*128 + orow))*C_ + h*64 + ocol;
  #pragma unroll
  for(int j=0;j<4;j++)
    *reinterpret_cast<v8bf*>(Og + j*8) = *reinterpret_cast<const v8bf*>(&Os[orow][ocol + j*8]);
}

// ---------------- launch ----------------
extern "C" void kernel_launch(void* const* d_in, const int* in_sizes, int n_in,
                              void* d_out, int out_size, void* d_ws, size_t ws_size,
                              hipStream_t stream) {
  const float* x      = (const float*)d_in[0];
  const float* w_qkv  = (const float*)d_in[1];
  const float* w_proj = (const float*)d_in[2];
  const float* b_proj = (const float*)d_in[3];
  const float* w1     = (const float*)d_in[4];
  const float* b1     = (const float*)d_in[5];
  const float* w2     = (const float*)d_in[6];
  const float* b2     = (const float*)d_in[7];
  const float* gamma1 = (const float*)d_in[8];
  const float* beta1  = (const float*)d_in[9];
  const float* gamma2 = (const float*)d_in[10];
  const float* beta2  = (const float*)d_in[11];

  char* ws = (char*)d_ws;
  bf16_t* wqkv_t  = (bf16_t*)(ws + 0);           // 3072x1024
  bf16_t* wproj_t = (bf16_t*)(ws + 6291456);     // 1024x1024
  bf16_t* w1_t    = (bf16_t*)(ws + 8388608);     // 4096x1024
  bf16_t* w2_t    = (bf16_t*)(ws + 16777216);    // 1024x4096
  bf16_t* qb      = (bf16_t*)(ws + 25165824);    // [B,H,T,D]
  bf16_t* kb      = (bf16_t*)(ws + 41943040);    // [B,H,T,D]
  bf16_t* vtb     = (bf16_t*)(ws + 58720256);    // [B,H,D,T]
  bf16_t* obuf    = (bf16_t*)(ws + 75497472);    // [B,T,C]
  bf16_t* hb      = (bf16_t*)(ws + 92274688);    // [M,C] bf16
  bf16_t* gb      = (bf16_t*)(ws + 25165824);    // [M,4C] bf16 (reuses q..o)
  float*  x2      = (float*)d_out;               // x after attn residual (aliases out)

  dim3 tb(32,8);
  k_transpose_cast<<<dim3(3072/32, 1024/32), tb, 0, stream>>>(w_qkv,  wqkv_t, 1024, 3072);
  k_transpose_cast<<<dim3(1024/32, 1024/32), tb, 0, stream>>>(w_proj, wproj_t,1024, 1024);
  k_transpose_cast<<<dim3(4096/32, 1024/32), tb, 0, stream>>>(w1,     w1_t,   1024, 4096);
  k_transpose_cast<<<dim3(1024/32, 4096/32), tb, 0, stream>>>(w2,     w2_t,   4096, 1024);

  k_layernorm<<<M_, 256, 0, stream>>>(x, gamma1, beta1, hb);

  k_gemm<0><<<dim3(24, 32), 512, 0, stream>>>(hb, wqkv_t, nullptr, nullptr,
                                              qb, kb, vtb, 3072, 1024, 24);
  k_attn<<<dim3(T_/128, B_*H_), 256, 0, stream>>>(qb, kb, vtb, obuf);

  k_gemm<1><<<dim3(8, 32), 512, 0, stream>>>(obuf, wproj_t, b_proj, x,
                                             x2, nullptr, nullptr, 1024, 1024, 8);
  k_layernorm<<<M_, 256, 0, stream>>>(x2, gamma2, beta2, hb);

  k_gemm<2><<<dim3(32, 32), 512, 0, stream>>>(hb, w1_t, b1, nullptr,
                                              gb, nullptr, nullptr, 4096, 1024, 32);
  k_gemm<3><<<dim3(8, 32), 512, 0, stream>>>(gb, w2_t, b2, x2,
                                             d_out, nullptr, nullptr, 1024, 4096, 8);
}

// Round 6
// 438.767 us; speedup vs baseline: 1.2838x; 1.1110x over previous
//
#include <hip/hip_runtime.h>
#include <hip/hip_bf16.h>
#include <cstdint>
#include <cstddef>

#define B_ 4
#define T_ 2048
#define C_ 1024
#define H_ 16
#define D_ 64
#define M_ (B_*T_)   // 8192 rows

using bf16_t = __hip_bfloat16;
typedef __bf16 v8bf __attribute__((ext_vector_type(8)));
typedef float  v4f  __attribute__((ext_vector_type(4)));
typedef float  f32x16 __attribute__((ext_vector_type(16)));

// 1/sqrt(D) * log2(e): folded into Q at the QKV epilogue; softmax in exp2 domain.
#define QSCALE (0.125f * 1.44269504088896340736f)

static __device__ __forceinline__ bf16_t f2bf(float v){ return __float2bfloat16(v); }

// async global->LDS, 16B per lane. LDS dest is wave-uniform base + lane*16.
static __device__ __forceinline__ void glds16(const bf16_t* g, bf16_t* l){
  __builtin_amdgcn_global_load_lds((__attribute__((address_space(1))) void*)g,
                                   (__attribute__((address_space(3))) void*)l, 16, 0, 0);
}

static __device__ __forceinline__ uint32_t cvt_pk_bf16(float lo, float hi){
  uint32_t w;
  asm("v_cvt_pk_bf16_f32 %0, %1, %2" : "=v"(w) : "v"(lo), "v"(hi));
  return w;
}

// ---------------- transpose + cast fp32[K][N] -> bf16[N][K] ----------------
__global__ void k_transpose_cast(const float* __restrict__ in, bf16_t* __restrict__ out,
                                 int K, int N){
  __shared__ float tile[32][33];
  int k0 = blockIdx.y*32, n0 = blockIdx.x*32;
  int tx = threadIdx.x, ty = threadIdx.y; // 32 x 8
  #pragma unroll
  for(int j=0;j<32;j+=8) tile[ty+j][tx] = in[(size_t)(k0+ty+j)*N + n0+tx];
  __syncthreads();
  #pragma unroll
  for(int j=0;j<32;j+=8) out[(size_t)(n0+ty+j)*K + k0+tx] = f2bf(tile[tx][ty+j]);
}

// ---------------- LayerNorm fp32 row -> bf16 row ----------------
__global__ __launch_bounds__(256) void k_layernorm(const float* __restrict__ x,
                                                   const float* __restrict__ gamma,
                                                   const float* __restrict__ beta,
                                                   bf16_t* __restrict__ out){
  int row = blockIdx.x;
  int tid = threadIdx.x;
  const float4 v = reinterpret_cast<const float4*>(x + (size_t)row*C_)[tid];
  float s  = v.x+v.y+v.z+v.w;
  float ss = v.x*v.x+v.y*v.y+v.z*v.z+v.w*v.w;
  #pragma unroll
  for(int m=1;m<64;m<<=1){ s += __shfl_xor(s,m); ss += __shfl_xor(ss,m); }
  __shared__ float sbuf[4], ssbuf[4];
  int wid = tid>>6, lane = tid&63;
  if(lane==0){ sbuf[wid]=s; ssbuf[wid]=ss; }
  __syncthreads();
  s  = sbuf[0]+sbuf[1]+sbuf[2]+sbuf[3];
  ss = ssbuf[0]+ssbuf[1]+ssbuf[2]+ssbuf[3];
  float mean = s * (1.0f/C_);
  float var  = ss * (1.0f/C_) - mean*mean;
  float rstd = rsqrtf(var + 1e-3f);
  const float4 g = reinterpret_cast<const float4*>(gamma)[tid];
  const float4 b = reinterpret_cast<const float4*>(beta)[tid];
  union { ushort4 u; bf16_t h[4]; } pk;
  pk.h[0] = f2bf(g.x*(v.x-mean)*rstd + b.x);
  pk.h[1] = f2bf(g.y*(v.y-mean)*rstd + b.y);
  pk.h[2] = f2bf(g.z*(v.z-mean)*rstd + b.z);
  pk.h[3] = f2bf(g.w*(v.w-mean)*rstd + b.w);
  *reinterpret_cast<ushort4*>(out + (size_t)row*C_ + tid*4) = pk.u;
}

// ---------------- GEMM: 256x128 tile, BK=32, 8 waves, counted-vmcnt double-buffer ----------------
// (unchanged from round 5 — verified structure)
template<int MODE>
__global__ __launch_bounds__(512, 4)
void k_gemm(const bf16_t* __restrict__ A, const bf16_t* __restrict__ Bt,
            const float* __restrict__ bias, const float* resid,
            void* out0, void* out1, void* out2,
            int N, int K, int gx)
{
  __shared__ __align__(16) bf16_t As[2][256*32];
  __shared__ __align__(16) bf16_t Bs[2][128*32];
  const int tid = threadIdx.x, lane = tid & 63, w = tid >> 6;   // 8 waves
  const int wm = w >> 1, wn = w & 1;                            // 4M x 2N, 64x64 each

  const int nwg = gx * 32;
  const int orig = blockIdx.y * gx + blockIdx.x;
  const int swz = (orig & 7) * (nwg >> 3) + (orig >> 3);
  const int ct = swz % gx, rt = swz / gx;
  const int row0 = rt * 256, col0 = ct * 128;

  const int sswz  = ((lane & 3) ^ ((lane >> 3) & 3)) * 8;
  const int srowA = w * 32 + (lane >> 2);
  const int srowB = w * 16 + (lane >> 2);
  const bf16_t* Ag = A  + (size_t)(row0 + srowA) * K + sswz;
  const bf16_t* Bg = Bt + (size_t)(col0 + srowB) * K + sswz;

  const int rdswz = (((lane >> 4) ^ (((lane & 15) >> 1) & 3))) * 8;

  v4f acc[4][4] = {};
  const int NT = K >> 5;

  auto stage = [&](int tt, int bb){
    const size_t ko = (size_t)tt * 32;
    glds16(Ag + ko,                 &As[bb][(w*32     )*32]);
    glds16(Ag + (size_t)16*K + ko,  &As[bb][(w*32 + 16)*32]);
    glds16(Bg + ko,                 &Bs[bb][(w*16     )*32]);
  };

  stage(0, 0);
  for (int t = 0; t < NT; ++t) {
    const int b = t & 1;
    if (t + 1 < NT) {
      stage(t + 1, b ^ 1);
      asm volatile("s_waitcnt vmcnt(3)" ::: "memory");
    } else {
      asm volatile("s_waitcnt vmcnt(0)" ::: "memory");
    }
    __builtin_amdgcn_s_barrier();
    __builtin_amdgcn_sched_barrier(0);
    const bf16_t* Ab = &As[b][0];
    const bf16_t* Bb = &Bs[b][0];
    v8bf af[4], bfv[4];
    #pragma unroll
    for (int m = 0; m < 4; ++m) {
      const int r = wm*64 + m*16 + (lane & 15);
      af[m] = *reinterpret_cast<const v8bf*>(Ab + r*32 + rdswz);
    }
    #pragma unroll
    for (int n = 0; n < 4; ++n) {
      const int r = wn*64 + n*16 + (lane & 15);
      bfv[n] = *reinterpret_cast<const v8bf*>(Bb + r*32 + rdswz);
    }
    __builtin_amdgcn_s_setprio(1);
    #pragma unroll
    for (int m = 0; m < 4; ++m)
      #pragma unroll
      for (int n = 0; n < 4; ++n)
        acc[m][n] = __builtin_amdgcn_mfma_f32_16x16x32_bf16(af[m], bfv[n], acc[m][n], 0,0,0);
    __builtin_amdgcn_s_setprio(0);
    __builtin_amdgcn_sched_barrier(0);
    __builtin_amdgcn_s_barrier();
  }

  #pragma unroll
  for (int mf = 0; mf < 4; ++mf) {
    const int rbase = row0 + wm*64 + mf*16 + (lane>>4)*4;
    #pragma unroll
    for (int nf = 0; nf < 4; ++nf) {
      const int c = col0 + wn*64 + nf*16 + (lane&15);
      #pragma unroll
      for (int i = 0; i < 4; ++i) {
        const int rr = rbase + i;
        float v = acc[mf][nf][i];
        if constexpr(MODE==0){
          const int sec = c >> 10, cc = c & 1023;
          const int h = cc >> 6, d = cc & 63;
          const int b = rr >> 11, t = rr & 2047;
          if(sec==0)      ((bf16_t*)out0)[((size_t)(b*H_ + h)*T_ + t)*D_ + d] = f2bf(v * QSCALE);
          else if(sec==1) ((bf16_t*)out1)[((size_t)(b*H_ + h)*T_ + t)*D_ + d] = f2bf(v);
          else            ((bf16_t*)out2)[((size_t)(b*H_ + h)*D_ + d)*T_ + t] = f2bf(v);
        } else if constexpr(MODE==1){
          ((float*)out0)[(size_t)rr*N + c] = v + bias[c] + resid[(size_t)rr*N + c];
        } else if constexpr(MODE==2){
          float o = v + bias[c];
          o = 0.5f*o*(1.0f + erff(o*0.70710678118f));
          ((bf16_t*)out0)[(size_t)rr*N + c] = f2bf(o);
        } else {
          ((float*)out0)[(size_t)rr*N + c] = v + bias[c] + resid[(size_t)rr*N + c];
        }
      }
    }
  }
}

// ---------------- causal flash attention, swapped-operand 32x32 ----------------
// Q(pre-scaled): [B,H,T,D] bf16 ; K: [B,H,T,D] bf16 ; Vt: [B,H,D,T] bf16 ; O: [B,T,C] bf16
// Uniform-work pairing: block (pair, bh) runs q-tile (15-pair) then (pair):
// (16-pair)*2 + (pair+1)*2 = 34 kv-tiles for every block -> no causal tail.
// T14: next K/V tile prefetched into regs under compute. T13: defer-max (THR=8, exp2 domain).
__global__ __launch_bounds__(256)
void k_attn(const bf16_t* __restrict__ Q, const bf16_t* __restrict__ Kg,
            const bf16_t* __restrict__ Vt, bf16_t* __restrict__ O)
{
  __shared__ __align__(16) bf16_t Ks [64][72];   // [kv][d]
  __shared__ __align__(16) bf16_t Vts[64][72];   // [d][kv]
  __shared__ __align__(16) bf16_t Os [128][72];  // [q][d] transpose buffer
  const int bh = blockIdx.y;
  const int pair = blockIdx.x;     // 0..7
  const int tid = threadIdx.x, lane = tid & 63, w = tid >> 6;
  const int ql = lane & 31, hi = lane >> 5;
  const int srow = tid >> 2;
  const int scol = (tid & 3) * 16;
  const bf16_t* Kgp = Kg + ((size_t)bh*T_ + srow)*D_ + scol;
  const bf16_t* Vtp = Vt + ((size_t)bh*D_ + srow)*T_ + scol;
  const int b = bh >> 4, h = bh & 15;

  for(int half=0; half<2; ++half){
    const int qt = half ? pair : (15 - pair);    // big job first
    const int qbase = qt*128 + w*32;
    const int q = qbase + ql;

    v8bf qf[4];
    {
      const bf16_t* Qb = Q + ((size_t)bh*T_ + q)*D_ + hi*8;
      #pragma unroll
      for(int ds=0; ds<4; ds++)
        qf[ds] = *reinterpret_cast<const v8bf*>(Qb + ds*16);
    }

    f32x16 accO[2] = {};        // O^T: col=q (lane-local), row d = dh*32 + (r&3)+8*(r>>2)+4*hi
    float mrun = -1e30f, lrun = 0.0f;
    const int NT = (qt + 1) * 2;

    // prefetch tile 0 into regs
    v8bf kr0 = *reinterpret_cast<const v8bf*>(Kgp);
    v8bf kr1 = *reinterpret_cast<const v8bf*>(Kgp + 8);
    v8bf vr0 = *reinterpret_cast<const v8bf*>(Vtp);
    v8bf vr1 = *reinterpret_cast<const v8bf*>(Vtp + 8);

    for(int t=0; t<NT; t++){
      const int kv0 = t*64;
      // write the prefetched tile to LDS
      *reinterpret_cast<v8bf*>(&Ks [srow][scol  ]) = kr0;
      *reinterpret_cast<v8bf*>(&Ks [srow][scol+8]) = kr1;
      *reinterpret_cast<v8bf*>(&Vts[srow][scol  ]) = vr0;
      *reinterpret_cast<v8bf*>(&Vts[srow][scol+8]) = vr1;
      __syncthreads();
      if(t+1 < NT){               // issue next tile's loads; latency hides under compute
        const size_t kn = (size_t)(kv0 + 64);
        kr0 = *reinterpret_cast<const v8bf*>(Kgp + kn*D_);
        kr1 = *reinterpret_cast<const v8bf*>(Kgp + kn*D_ + 8);
        vr0 = *reinterpret_cast<const v8bf*>(Vtp + kn);
        vr1 = *reinterpret_cast<const v8bf*>(Vtp + kn + 8);
      }

      if(kv0 <= qbase + 31){      // wave-uniform: skip fully-masked tiles
        // S^T = K * Q^T
        f32x16 sT[2] = {};
        #pragma unroll
        for(int kvh=0; kvh<2; kvh++)
          #pragma unroll
          for(int ds=0; ds<4; ds++){
            v8bf kf = *reinterpret_cast<const v8bf*>(&Ks[kvh*32 + ql][ds*16 + hi*8]);
            sT[kvh] = __builtin_amdgcn_mfma_f32_32x32x16_bf16(kf, qf[ds], sT[kvh], 0,0,0);
          }

        if(kv0 + 63 > qbase){     // diagonal tile: causal mask
          const int qrel = q - kv0 - hi*4;
          #pragma unroll
          for(int kvh=0; kvh<2; kvh++)
            #pragma unroll
            for(int r=0; r<16; r++){
              const int c = kvh*32 + (r&3) + 8*(r>>2);
              if(c > qrel) sT[kvh][r] = -1e30f;
            }
        }

        // row max (in-lane + partner half)
        float pm = sT[0][0];
        #pragma unroll
        for(int r=1; r<16; r++) pm = fmaxf(pm, sT[0][r]);
        #pragma unroll
        for(int r=0; r<16; r++) pm = fmaxf(pm, sT[1][r]);
        pm = fmaxf(pm, __shfl_xor(pm, 32));

        // T13 defer-max: only rescale when the max moved by >8 (exp2 domain; P <= 2^8)
        if(__any(pm - mrun > 8.0f)){
          const float mnew = fmaxf(mrun, pm);
          const float corr = __builtin_amdgcn_exp2f(mrun - mnew);
          mrun = mnew;
          lrun *= corr;
          #pragma unroll
          for(int dh=0; dh<2; dh++)
            #pragma unroll
            for(int r=0; r<16; r++) accO[dh][r] *= corr;
        }

        float rs = 0.0f;
        #pragma unroll
        for(int kvh=0; kvh<2; kvh++)
          #pragma unroll
          for(int r=0; r<16; r++){
            float p = __builtin_amdgcn_exp2f(sT[kvh][r] - mrun);
            sT[kvh][r] = p;
            rs += p;
          }
        rs += __shfl_xor(rs, 32);
        lrun += rs;

        // pack P -> bf16 B-operand fragments (verified shfl_xor(32) exchange)
        v8bf pfrag[4];
        #pragma unroll
        for(int s4=0; s4<4; s4++){
          const int kvh = s4>>1, bb = (s4&1)*8;
          uint32_t wa = cvt_pk_bf16(sT[kvh][bb+0], sT[kvh][bb+1]);
          uint32_t wb = cvt_pk_bf16(sT[kvh][bb+2], sT[kvh][bb+3]);
          uint32_t wc = cvt_pk_bf16(sT[kvh][bb+4], sT[kvh][bb+5]);
          uint32_t wd = cvt_pk_bf16(sT[kvh][bb+6], sT[kvh][bb+7]);
          uint32_t xwa = (uint32_t)__shfl_xor((int)wa, 32);
          uint32_t xwb = (uint32_t)__shfl_xor((int)wb, 32);
          uint32_t xwc = (uint32_t)__shfl_xor((int)wc, 32);
          uint32_t xwd = (uint32_t)__shfl_xor((int)wd, 32);
          union { uint32_t u[4]; v8bf v; } pk;
          pk.u[0] = hi ? xwc : wa;
          pk.u[1] = hi ? xwd : wb;
          pk.u[2] = hi ? wc  : xwa;
          pk.u[3] = hi ? wd  : xwb;
          pfrag[s4] = pk.v;
        }

        // O^T += V^T * P^T
        #pragma unroll
        for(int dh=0; dh<2; dh++)
          #pragma unroll
          for(int s4=0; s4<4; s4++){
            v8bf vf = *reinterpret_cast<const v8bf*>(&Vts[dh*32 + ql][s4*16 + hi*8]);
            accO[dh] = __builtin_amdgcn_mfma_f32_32x32x16_bf16(vf, pfrag[s4], accO[dh], 0,0,0);
          }
      }
      __syncthreads();
    }

    // normalize (lane-local) and transpose through LDS for coalesced store
    const float inv = 1.0f / lrun;
    #pragma unroll
    for(int dh=0; dh<2; dh++)
      #pragma unroll
      for(int rg=0; rg<4; rg++){
        uint32_t lo_ = cvt_pk_bf16(accO[dh][rg*4+0]*inv, accO[dh][rg*4+1]*inv);
        uint32_t hi_ = cvt_pk_bf16(accO[dh][rg*4+2]*inv, accO[dh][rg*4+3]*inv);
        uint2 w2; w2.x = lo_; w2.y = hi_;
        *reinterpret_cast<uint2*>(&Os[w*32 + ql][dh*32 + rg*8 + hi*4]) = w2;
      }
    __syncthreads();
    const int orow = tid >> 1, ocol = (tid & 1) * 32;
    bf16_t* Og = O + ((size_t)(b*T_ + qt*128 + orow))*C_ + h*64 + ocol;
    #pragma unroll
    for(int j=0;j<4;j++)
      *reinterpret_cast<v8bf*>(Og + j*8) = *reinterpret_cast<const v8bf*>(&Os[orow][ocol + j*8]);
    __syncthreads();   // protect Os/Ks/Vts before next half re-stages
  }
}

// ---------------- launch ----------------
extern "C" void kernel_launch(void* const* d_in, const int* in_sizes, int n_in,
                              void* d_out, int out_size, void* d_ws, size_t ws_size,
                              hipStream_t stream) {
  const float* x      = (const float*)d_in[0];
  const float* w_qkv  = (const float*)d_in[1];
  const float* w_proj = (const float*)d_in[2];
  const float* b_proj = (const float*)d_in[3];
  const float* w1     = (const float*)d_in[4];
  const float* b1     = (const float*)d_in[5];
  const float* w2     = (const float*)d_in[6];
  const float* b2     = (const float*)d_in[7];
  const float* gamma1 = (const float*)d_in[8];
  const float* beta1  = (const float*)d_in[9];
  const float* gamma2 = (const float*)d_in[10];
  const float* beta2  = (const float*)d_in[11];

  char* ws = (char*)d_ws;
  bf16_t* wqkv_t  = (bf16_t*)(ws + 0);           // 3072x1024
  bf16_t* wproj_t = (bf16_t*)(ws + 6291456);     // 1024x1024
  bf16_t* w1_t    = (bf16_t*)(ws + 8388608);     // 4096x1024
  bf16_t* w2_t    = (bf16_t*)(ws + 16777216);    // 1024x4096
  bf16_t* qb      = (bf16_t*)(ws + 25165824);    // [B,H,T,D]
  bf16_t* kb      = (bf16_t*)(ws + 41943040);    // [B,H,T,D]
  bf16_t* vtb     = (bf16_t*)(ws + 58720256);    // [B,H,D,T]
  bf16_t* obuf    = (bf16_t*)(ws + 75497472);    // [B,T,C]
  bf16_t* hb      = (bf16_t*)(ws + 92274688);    // [M,C] bf16
  bf16_t* gb      = (bf16_t*)(ws + 25165824);    // [M,4C] bf16 (reuses q..o)
  float*  x2      = (float*)d_out;               // x after attn residual (aliases out)

  dim3 tb(32,8);
  k_transpose_cast<<<dim3(3072/32, 1024/32), tb, 0, stream>>>(w_qkv,  wqkv_t, 1024, 3072);
  k_transpose_cast<<<dim3(1024/32, 1024/32), tb, 0, stream>>>(w_proj, wproj_t,1024, 1024);
  k_transpose_cast<<<dim3(4096/32, 1024/32), tb, 0, stream>>>(w1,     w1_t,   1024, 4096);
  k_transpose_cast<<<dim3(1024/32, 4096/32), tb, 0, stream>>>(w2,     w2_t,   4096, 1024);

  k_layernorm<<<M_, 256, 0, stream>>>(x, gamma1, beta1, hb);

  k_gemm<0><<<dim3(24, 32), 512, 0, stream>>>(hb, wqkv_t, nullptr, nullptr,
                                              qb, kb, vtb, 3072, 1024, 24);
  k_attn<<<dim3(8, B_*H_), 256, 0, stream>>>(qb, kb, vtb, obuf);

  k_gemm<1><<<dim3(8, 32), 512, 0, stream>>>(obuf, wproj_t, b_proj, x,
                                             x2, nullptr, nullptr, 1024, 1024, 8);
  k_layernorm<<<M_, 256, 0, stream>>>(x2, gamma2, beta2, hb);

  k_gemm<2><<<dim3(32, 32), 512, 0, stream>>>(hb, w1_t, b1, nullptr,
                                              gb, nullptr, nullptr, 4096, 1024, 32);
  k_gemm<3><<<dim3(8, 32), 512, 0, stream>>>(gb, w2_t, b2, x2,
                                             d_out, nullptr, nullptr, 1024, 4096, 8);
}